// Round 2
// baseline (483.393 us; speedup 1.0000x reference)
//
#include <hip/hip_runtime.h>
#include <hip/hip_bf16.h>

typedef unsigned short u16;
typedef __attribute__((ext_vector_type(4))) float f32x4;
typedef __attribute__((ext_vector_type(8))) short short8;
typedef __attribute__((ext_vector_type(4))) unsigned short ushort4v;

// ---------- helpers ----------
__device__ __forceinline__ u16 f2bfu(float f) {
  unsigned int u = __float_as_uint(f);
  u += 0x7FFFu + ((u >> 16) & 1u);   // RNE
  return (u16)(u >> 16);
}
__device__ __forceinline__ float bfu2f(u16 h) {
  return __uint_as_float(((unsigned int)h) << 16);
}
__device__ __forceinline__ f32x4 mfma16(short8 a, short8 b, f32x4 c) {
  return __builtin_amdgcn_mfma_f32_16x16x32_bf16(a, b, c, 0, 0, 0);
}
__device__ __forceinline__ void gld16(const void* g, void* l) {
  __builtin_amdgcn_global_load_lds(
      (const __attribute__((address_space(1))) void*)g,
      (__attribute__((address_space(3))) void*)l, 16, 0, 0);
}

// ---------- fp32 -> bf16 convert ----------
__global__ void k_cvt(const float* __restrict__ src, u16* __restrict__ dst, int n4) {
  int i = blockIdx.x * blockDim.x + threadIdx.x;
  if (i < n4) {
    float4 v = ((const float4*)src)[i];
    ushort4v o;
    o.x = f2bfu(v.x); o.y = f2bfu(v.y); o.z = f2bfu(v.z); o.w = f2bfu(v.w);
    *(ushort4v*)(dst + (size_t)i * 4) = o;
  }
}

// ---------- router logits (fp32, one wave per token) ----------
__global__ void k_router(const float* __restrict__ x, const float* __restrict__ wr,
                         float* __restrict__ logits, float* __restrict__ out_lg) {
  int t = blockIdx.x * 4 + (threadIdx.x >> 6);
  int l = threadIdx.x & 63;
  const float* xp = x + (size_t)t * 1024;
  float s = 0.f;
#pragma unroll
  for (int p = 0; p < 4; ++p) {
    float4 xv = *(const float4*)(xp + (p * 64 + l) * 4);
    float4 wv = *(const float4*)(wr + (p * 64 + l) * 4);
    s += xv.x * wv.x + xv.y * wv.y + xv.z * wv.z + xv.w * wv.w;
  }
#pragma unroll
  for (int off = 32; off; off >>= 1) s += __shfl_xor(s, off);
  if (l == 0) { logits[t] = s; out_lg[t] = s; }
}

// ---------- top-k mask by rank counting (ties: lower index wins) ----------
__global__ void k_mask(const float* __restrict__ logits, float* __restrict__ mask) {
  __shared__ float lg[2048];
  int b = blockIdx.x >> 3;
  int i = (blockIdx.x & 7) * 256 + threadIdx.x;
  const float* lp = logits + b * 2048;
  for (int j = threadIdx.x; j < 2048; j += 256) lg[j] = lp[j];
  __syncthreads();
  float my = lg[i];
  int cnt = 0;
  for (int j = 0; j < 2048; ++j) {
    float v = lg[j];
    cnt += (v > my) || (v == my && j < i);
  }
  mask[b * 2048 + i] = (cnt < 1024) ? 1.0f : 0.0f;
}

// ---------- LayerNorm (fp32 in, bf16 out); one wave per token ----------
__global__ void k_ln(const float* __restrict__ x, const float* __restrict__ g,
                     const float* __restrict__ bb, u16* __restrict__ out) {
  int t = blockIdx.x * 4 + (threadIdx.x >> 6);
  int l = threadIdx.x & 63;
  const float* xp = x + (size_t)t * 1024;
  float4 xv[4];
  float s = 0.f, sq = 0.f;
#pragma unroll
  for (int p = 0; p < 4; ++p) {
    xv[p] = *(const float4*)(xp + (p * 64 + l) * 4);
    s += xv[p].x + xv[p].y + xv[p].z + xv[p].w;
    sq += xv[p].x * xv[p].x + xv[p].y * xv[p].y + xv[p].z * xv[p].z + xv[p].w * xv[p].w;
  }
#pragma unroll
  for (int off = 32; off; off >>= 1) { s += __shfl_xor(s, off); sq += __shfl_xor(sq, off); }
  float mu = s * (1.f / 1024.f);
  float var = sq * (1.f / 1024.f) - mu * mu;
  float rs = rsqrtf(var + 1e-6f);
#pragma unroll
  for (int p = 0; p < 4; ++p) {
    float4 gv = *(const float4*)(g + (p * 64 + l) * 4);
    float4 bv = *(const float4*)(bb + (p * 64 + l) * 4);
    ushort4v o;
    o.x = f2bfu((xv[p].x - mu) * rs * gv.x + bv.x);
    o.y = f2bfu((xv[p].y - mu) * rs * gv.y + bv.y);
    o.z = f2bfu((xv[p].z - mu) * rs * gv.z + bv.z);
    o.w = f2bfu((xv[p].w - mu) * rs * gv.w + bv.w);
    *(ushort4v*)(out + (size_t)t * 1024 + (p * 64 + l) * 4) = o;
  }
}

// ---------- common 128x128xBK64 GEMM core: C = A[M,K] * W[N,K]^T ----------
__device__ __forceinline__ void gemm_core64(
    const u16* __restrict__ A, const u16* __restrict__ W,
    u16 (&Al)[2][128][64], u16 (&Bl)[2][128][64],
    int m0, int n0, int K, f32x4 (&acc)[4][4]) {
  const int tid = threadIdx.x, w = tid >> 6, l = tid & 63;
  const int wr = (w >> 1) * 64, wc = (w & 1) * 64;
#pragma unroll
  for (int mt = 0; mt < 4; ++mt)
#pragma unroll
    for (int nt = 0; nt < 4; ++nt) acc[mt][nt] = (f32x4){0.f, 0.f, 0.f, 0.f};
  const int nsteps = K >> 6;

  auto stage = [&](int bf, int t) {
#pragma unroll
    for (int i = 0; i < 4; ++i) {
      const int bc = (i * 4 + w) * 64;
      const int chunk = bc + l;
      const int row = chunk >> 3, cc = chunk & 7;
      gld16(A + (size_t)(m0 + row) * K + t * 64 + cc * 8, (char*)(&Al[bf][0][0]) + bc * 16);
      gld16(W + (size_t)(n0 + row) * K + t * 64 + cc * 8, (char*)(&Bl[bf][0][0]) + bc * 16);
    }
  };

  stage(0, 0);
  for (int t = 0; t < nsteps; ++t) {
    __syncthreads();
    if (t + 1 < nsteps) stage((t + 1) & 1, t + 1);
    const int bf = t & 1;
#pragma unroll
    for (int kk = 0; kk < 2; ++kk) {
      const int ko = kk * 32 + (l >> 4) * 8;
      short8 af[4], bv[4];
#pragma unroll
      for (int mt = 0; mt < 4; ++mt) af[mt] = *(const short8*)&Al[bf][wr + mt * 16 + (l & 15)][ko];
#pragma unroll
      for (int nt = 0; nt < 4; ++nt) bv[nt] = *(const short8*)&Bl[bf][wc + nt * 16 + (l & 15)][ko];
#pragma unroll
      for (int mt = 0; mt < 4; ++mt)
#pragma unroll
        for (int nt = 0; nt < 4; ++nt)
          acc[mt][nt] = mfma16(af[mt], bv[nt], acc[mt][nt]);
    }
  }
}

// ---------- fused QKV projection (bf16 out) ----------
__global__ __launch_bounds__(256, 2)
void k_qkv(const u16* __restrict__ A,
           const u16* __restrict__ W0, const u16* __restrict__ W1, const u16* __restrict__ W2,
           u16* __restrict__ O0, u16* __restrict__ O1, u16* __restrict__ O2, int K) {
  __shared__ alignas(16) u16 Al[2][128][64];
  __shared__ alignas(16) u16 Bl[2][128][64];
  const int sel = blockIdx.x >> 3;
  const u16* W = sel == 0 ? W0 : (sel == 1 ? W1 : W2);
  u16* Ot = sel == 0 ? O0 : (sel == 1 ? O1 : O2);
  const int n0 = (blockIdx.x & 7) * 128, m0 = blockIdx.y * 128;
  f32x4 acc[4][4];
  gemm_core64(A, W, Al, Bl, m0, n0, K, acc);
  const int tid = threadIdx.x, w = tid >> 6, l = tid & 63;
  const int wr = (w >> 1) * 64, wc = (w & 1) * 64;
#pragma unroll
  for (int mt = 0; mt < 4; ++mt)
#pragma unroll
    for (int nt = 0; nt < 4; ++nt) {
      int row = m0 + wr + mt * 16 + ((l >> 4) << 2);
      int col = n0 + wc + nt * 16 + (l & 15);
#pragma unroll
      for (int r = 0; r < 4; ++r)
        Ot[(size_t)(row + r) * 1024 + col] = f2bfu(acc[mt][nt][r]);
    }
}

// ---------- projection GEMM with fused residual + routing-mask epilogue ----------
__global__ __launch_bounds__(256, 2)
void k_proj_resid(const u16* __restrict__ A, const u16* __restrict__ W,
                  const float* __restrict__ resid, const float* __restrict__ mask,
                  float* __restrict__ out, int N, int K) {
  __shared__ alignas(16) u16 Al[2][128][64];
  __shared__ alignas(16) u16 Bl[2][128][64];
  const int n0 = blockIdx.x * 128, m0 = blockIdx.y * 128;
  f32x4 acc[4][4];
  gemm_core64(A, W, Al, Bl, m0, n0, K, acc);
  const int tid = threadIdx.x, w = tid >> 6, l = tid & 63;
  const int wr = (w >> 1) * 64, wc = (w & 1) * 64;
#pragma unroll
  for (int mt = 0; mt < 4; ++mt)
#pragma unroll
    for (int nt = 0; nt < 4; ++nt) {
      int row = m0 + wr + mt * 16 + ((l >> 4) << 2);
      int col = n0 + wc + nt * 16 + (l & 15);
#pragma unroll
      for (int r = 0; r < 4; ++r) {
        size_t idx = (size_t)(row + r) * N + col;
        out[idx] = resid[idx] + mask[row + r] * acc[mt][nt][r];
      }
    }
}

// ---------- fused dual gate/up GEMM (BK=32) with silu(g)*u epilogue ----------
__global__ __launch_bounds__(256, 2)
void k_ffn_dual(const u16* __restrict__ A, const u16* __restrict__ Wg, const u16* __restrict__ Wu,
                u16* __restrict__ H, int N, int K) {
  __shared__ alignas(16) u16 Al[2][128][32];
  __shared__ alignas(16) u16 Bgl[2][128][32];
  __shared__ alignas(16) u16 Bul[2][128][32];
  const int tid = threadIdx.x, w = tid >> 6, l = tid & 63;
  const int n0 = blockIdx.x * 128, m0 = blockIdx.y * 128;
  const int wr = (w >> 1) * 64, wc = (w & 1) * 64;
  f32x4 ag[4][4], au[4][4];
#pragma unroll
  for (int mt = 0; mt < 4; ++mt)
#pragma unroll
    for (int nt = 0; nt < 4; ++nt) {
      ag[mt][nt] = (f32x4){0.f, 0.f, 0.f, 0.f};
      au[mt][nt] = (f32x4){0.f, 0.f, 0.f, 0.f};
    }
  const int nsteps = K >> 5;

  auto stage = [&](int bf, int t) {
#pragma unroll
    for (int i = 0; i < 2; ++i) {
      const int bc = (i * 4 + w) * 64;
      const int chunk = bc + l;
      const int row = chunk >> 2, cc = chunk & 3;
      const size_t ao = (size_t)(m0 + row) * K + t * 32 + cc * 8;
      const size_t bo = (size_t)(n0 + row) * K + t * 32 + cc * 8;
      gld16(A + ao,  (char*)(&Al[bf][0][0])  + bc * 16);
      gld16(Wg + bo, (char*)(&Bgl[bf][0][0]) + bc * 16);
      gld16(Wu + bo, (char*)(&Bul[bf][0][0]) + bc * 16);
    }
  };

  stage(0, 0);
  for (int t = 0; t < nsteps; ++t) {
    __syncthreads();
    if (t + 1 < nsteps) stage((t + 1) & 1, t + 1);
    const int bf = t & 1;
    const int ko = (l >> 4) * 8;
    short8 af[4], bg[4], bu[4];
#pragma unroll
    for (int mt = 0; mt < 4; ++mt) af[mt] = *(const short8*)&Al[bf][wr + mt * 16 + (l & 15)][ko];
#pragma unroll
    for (int nt = 0; nt < 4; ++nt) {
      bg[nt] = *(const short8*)&Bgl[bf][wc + nt * 16 + (l & 15)][ko];
      bu[nt] = *(const short8*)&Bul[bf][wc + nt * 16 + (l & 15)][ko];
    }
#pragma unroll
    for (int mt = 0; mt < 4; ++mt)
#pragma unroll
      for (int nt = 0; nt < 4; ++nt) {
        ag[mt][nt] = mfma16(af[mt], bg[nt], ag[mt][nt]);
        au[mt][nt] = mfma16(af[mt], bu[nt], au[mt][nt]);
      }
  }
#pragma unroll
  for (int mt = 0; mt < 4; ++mt)
#pragma unroll
    for (int nt = 0; nt < 4; ++nt) {
      int row = m0 + wr + mt * 16 + ((l >> 4) << 2);
      int col = n0 + wc + nt * 16 + (l & 15);
#pragma unroll
      for (int r = 0; r < 4; ++r) {
        float g = ag[mt][nt][r], u = au[mt][nt][r];
        float sg = g / (1.f + __expf(-g));
        H[(size_t)(row + r) * N + col] = f2bfu(sg * u);
      }
    }
}

// ---------- flash causal attention: 4 waves x 16 q-rows, KV tile 64, hd=64 ----------
__global__ __launch_bounds__(256, 2)
void k_attn(const u16* __restrict__ Q, const u16* __restrict__ K,
            const u16* __restrict__ V, u16* __restrict__ O) {
  const int S = 2048, HH = 1024;
  const int qt = blockIdx.x;            // 0..31 (q tile of 64)
  const int bh = blockIdx.y;            // 0..31
  const int b = bh >> 4, h = bh & 15;
  const int tid = threadIdx.x, w = tid >> 6, l = tid & 63;
  __shared__ alignas(16) u16 Kl[64][72];
  __shared__ alignas(16) u16 Vt[64][72];
  __shared__ alignas(16) u16 Pl[4][16][72];
  const size_t base = ((size_t)b * S) * HH + h * 64;
  const int qr0 = qt * 64 + w * 16 + ((l >> 4) << 2);   // first of this lane's 4 acc rows
  const int qrow = qt * 64 + w * 16 + (l & 15);         // A-frag row

  short8 qf[2];
#pragma unroll
  for (int kk = 0; kk < 2; ++kk)
    qf[kk] = *(const short8*)&Q[base + (size_t)qrow * HH + kk * 32 + (l >> 4) * 8];

  f32x4 accO[4];
  float m[4], ls[4];
#pragma unroll
  for (int dt = 0; dt < 4; ++dt) accO[dt] = (f32x4){0.f, 0.f, 0.f, 0.f};
#pragma unroll
  for (int r = 0; r < 4; ++r) { m[r] = -1e30f; ls[r] = 0.f; }

  for (int kt = 0; kt <= qt; ++kt) {
    __syncthreads();
    // stage K tile [64][64] (rows of K are B-frags directly)
#pragma unroll
    for (int i = 0; i < 2; ++i) {
      int c = i * 256 + tid;
      int row = c >> 3, cc = c & 7;
      *(short8*)&Kl[row][cc * 8] =
          *(const short8*)&K[base + (size_t)(kt * 64 + row) * HH + cc * 8];
    }
    // stage V transposed: Vt[d][s] = V[s][d]
#pragma unroll
    for (int i = 0; i < 2; ++i) {
      int c = i * 256 + tid;
      int s = c >> 3, dc = c & 7;
      short8 vv = *(const short8*)&V[base + (size_t)(kt * 64 + s) * HH + dc * 8];
#pragma unroll
      for (int j = 0; j < 8; ++j) Vt[dc * 8 + j][s] = (u16)vv[j];
    }
    __syncthreads();

    // QK^T : 4 column tiles of 16
    float p[4][4];
    const bool diag = (kt == qt);
    const int kcb = kt * 64 + (l & 15);
#pragma unroll
    for (int ct = 0; ct < 4; ++ct) {
      f32x4 a = (f32x4){0.f, 0.f, 0.f, 0.f};
#pragma unroll
      for (int kk = 0; kk < 2; ++kk) {
        short8 kf = *(const short8*)&Kl[ct * 16 + (l & 15)][kk * 32 + (l >> 4) * 8];
        a = mfma16(qf[kk], kf, a);
      }
#pragma unroll
      for (int r = 0; r < 4; ++r) {
        float v = a[r] * 0.125f;
        if (diag && (kcb + ct * 16) > (qr0 + r)) v = -1e30f;
        p[ct][r] = v;
      }
    }
    // online softmax (rows live across the 16 lanes sharing l>>4)
    // NOTE: alpha is PER ROW r — scale only element [r] of each accO vector.
#pragma unroll
    for (int r = 0; r < 4; ++r) {
      float mx = fmaxf(fmaxf(p[0][r], p[1][r]), fmaxf(p[2][r], p[3][r]));
#pragma unroll
      for (int off = 1; off < 16; off <<= 1) mx = fmaxf(mx, __shfl_xor(mx, off));
      float mn = fmaxf(m[r], mx);
      float alpha = __expf(m[r] - mn);
      m[r] = mn;
      float ps = 0.f;
#pragma unroll
      for (int ct = 0; ct < 4; ++ct) { float e = __expf(p[ct][r] - mn); p[ct][r] = e; ps += e; }
#pragma unroll
      for (int off = 1; off < 16; off <<= 1) ps += __shfl_xor(ps, off);
      ls[r] = ls[r] * alpha + ps;
#pragma unroll
      for (int dt = 0; dt < 4; ++dt) accO[dt][r] *= alpha;
    }
    // P (C-layout) -> wave-private LDS -> A-frag layout
#pragma unroll
    for (int ct = 0; ct < 4; ++ct)
#pragma unroll
      for (int r = 0; r < 4; ++r)
        Pl[w][((l >> 4) << 2) + r][ct * 16 + (l & 15)] = f2bfu(p[ct][r]);
    short8 pa[2];
#pragma unroll
    for (int kk = 0; kk < 2; ++kk)
      pa[kk] = *(const short8*)&Pl[w][l & 15][kk * 32 + (l >> 4) * 8];
    // PV
#pragma unroll
    for (int dt = 0; dt < 4; ++dt)
#pragma unroll
      for (int kk = 0; kk < 2; ++kk) {
        short8 vf = *(const short8*)&Vt[dt * 16 + (l & 15)][kk * 32 + (l >> 4) * 8];
        accO[dt] = mfma16(pa[kk], vf, accO[dt]);
      }
  }
  // epilogue
#pragma unroll
  for (int dt = 0; dt < 4; ++dt)
#pragma unroll
    for (int r = 0; r < 4; ++r) {
      float v = accO[dt][r] / ls[r];
      O[base + (size_t)(qr0 + r) * HH + dt * 16 + (l & 15)] = f2bfu(v);
    }
}

extern "C" void kernel_launch(void* const* d_in, const int* in_sizes, int n_in,
                              void* d_out, int out_size, void* d_ws, size_t ws_size,
                              hipStream_t stream) {
  const float* x  = (const float*)d_in[0];
  const float* wr = (const float*)d_in[1];
  const float* g1 = (const float*)d_in[2];
  const float* b1 = (const float*)d_in[3];
  const float* wq = (const float*)d_in[4];
  const float* wk = (const float*)d_in[5];
  const float* wv = (const float*)d_in[6];
  const float* wo = (const float*)d_in[7];
  const float* g2 = (const float*)d_in[8];
  const float* b2 = (const float*)d_in[9];
  const float* wg = (const float*)d_in[10];
  const float* wu = (const float*)d_in[11];
  const float* wd = (const float*)d_in[12];

  float* out_x  = (float*)d_out;
  float* out_lg = out_x + (size_t)4096 * 1024;

  char* p = (char*)d_ws;
  float* mask   = (float*)p;             p += 16384;
  float* logits = (float*)p;             p += 16384;
  u16* wq_b = (u16*)p;                   p += (size_t)1048576 * 2;
  u16* wk_b = (u16*)p;                   p += (size_t)1048576 * 2;
  u16* wv_b = (u16*)p;                   p += (size_t)1048576 * 2;
  u16* wo_b = (u16*)p;                   p += (size_t)1048576 * 2;
  u16* wg_b = (u16*)p;                   p += (size_t)4194304 * 2;
  u16* wu_b = (u16*)p;                   p += (size_t)4194304 * 2;
  u16* wd_b = (u16*)p;                   p += (size_t)4194304 * 2;
  u16* xn   = (u16*)p;                   p += (size_t)4194304 * 2;  // reused for xn2
  u16* q_b  = (u16*)p;                   p += (size_t)4194304 * 2;
  u16* k_b  = (u16*)p;                   p += (size_t)4194304 * 2;
  u16* v_b  = (u16*)p;                   p += (size_t)4194304 * 2;
  u16* ao_b = (u16*)p;                   p += (size_t)4194304 * 2;
  u16* h_b  = q_b;  // [4096][4096] bf16 reuses q/k/v/ao region after attention+O-proj

  // weight conversions
  k_cvt<<<1024, 256, 0, stream>>>(wq, wq_b, 262144);
  k_cvt<<<1024, 256, 0, stream>>>(wk, wk_b, 262144);
  k_cvt<<<1024, 256, 0, stream>>>(wv, wv_b, 262144);
  k_cvt<<<1024, 256, 0, stream>>>(wo, wo_b, 262144);
  k_cvt<<<4096, 256, 0, stream>>>(wg, wg_b, 1048576);
  k_cvt<<<4096, 256, 0, stream>>>(wu, wu_b, 1048576);
  k_cvt<<<4096, 256, 0, stream>>>(wd, wd_b, 1048576);

  // router + mask
  k_router<<<1024, 256, 0, stream>>>(x, wr, logits, out_lg);
  k_mask<<<16, 256, 0, stream>>>(logits, mask);

  // attention sub-block
  k_ln<<<1024, 256, 0, stream>>>(x, g1, b1, xn);
  k_qkv<<<dim3(24, 32), 256, 0, stream>>>(xn, wq_b, wk_b, wv_b, q_b, k_b, v_b, 1024);
  k_attn<<<dim3(32, 32), 256, 0, stream>>>(q_b, k_b, v_b, ao_b);
  k_proj_resid<<<dim3(8, 32), 256, 0, stream>>>(ao_b, wo_b, x, mask, out_x, 1024, 1024);

  // FFN sub-block
  k_ln<<<1024, 256, 0, stream>>>(out_x, g2, b2, xn);
  k_ffn_dual<<<dim3(32, 32), 256, 0, stream>>>(xn, wg_b, wu_b, h_b, 4096, 1024);
  k_proj_resid<<<dim3(8, 32), 256, 0, stream>>>(h_b, wd_b, out_x, mask, out_x, 1024, 4096);
}

// Round 3
// 349.668 us; speedup vs baseline: 1.3824x; 1.3824x over previous
//
#include <hip/hip_runtime.h>
#include <hip/hip_bf16.h>

typedef unsigned short u16;
typedef __attribute__((ext_vector_type(4))) float f32x4;
typedef __attribute__((ext_vector_type(8))) short short8;
typedef __attribute__((ext_vector_type(4))) unsigned short ushort4v;

// ---------- helpers ----------
__device__ __forceinline__ u16 f2bfu(float f) {
  unsigned int u = __float_as_uint(f);
  u += 0x7FFFu + ((u >> 16) & 1u);   // RNE
  return (u16)(u >> 16);
}
__device__ __forceinline__ f32x4 mfma16(short8 a, short8 b, f32x4 c) {
  return __builtin_amdgcn_mfma_f32_16x16x32_bf16(a, b, c, 0, 0, 0);
}
__device__ __forceinline__ void gld16(const void* g, void* l) {
  __builtin_amdgcn_global_load_lds(
      (const __attribute__((address_space(1))) void*)g,
      (__attribute__((address_space(3))) void*)l, 16, 0, 0);
}

// ---------- fp32 -> bf16 convert, all 7 weights in one launch ----------
__global__ void k_cvt7(const float* __restrict__ s0, const float* __restrict__ s1,
                       const float* __restrict__ s2, const float* __restrict__ s3,
                       const float* __restrict__ s4, const float* __restrict__ s5,
                       const float* __restrict__ s6,
                       u16* __restrict__ d0, u16* __restrict__ d1, u16* __restrict__ d2,
                       u16* __restrict__ d3, u16* __restrict__ d4, u16* __restrict__ d5,
                       u16* __restrict__ d6) {
  const int y = blockIdx.y;
  const float* src; u16* dst; int n4;
  switch (y) {
    case 0: src = s0; dst = d0; n4 = 262144; break;
    case 1: src = s1; dst = d1; n4 = 262144; break;
    case 2: src = s2; dst = d2; n4 = 262144; break;
    case 3: src = s3; dst = d3; n4 = 262144; break;
    case 4: src = s4; dst = d4; n4 = 1048576; break;
    case 5: src = s5; dst = d5; n4 = 1048576; break;
    default: src = s6; dst = d6; n4 = 1048576; break;
  }
  int i = blockIdx.x * blockDim.x + threadIdx.x;
  if (i < n4) {
    float4 v = ((const float4*)src)[i];
    ushort4v o;
    o.x = f2bfu(v.x); o.y = f2bfu(v.y); o.z = f2bfu(v.z); o.w = f2bfu(v.w);
    *(ushort4v*)(dst + (size_t)i * 4) = o;
  }
}

// ---------- router logits (fp32, one wave per token) ----------
__global__ void k_router(const float* __restrict__ x, const float* __restrict__ wr,
                         float* __restrict__ logits, float* __restrict__ out_lg) {
  int t = blockIdx.x * 4 + (threadIdx.x >> 6);
  int l = threadIdx.x & 63;
  const float* xp = x + (size_t)t * 1024;
  float s = 0.f;
#pragma unroll
  for (int p = 0; p < 4; ++p) {
    float4 xv = *(const float4*)(xp + (p * 64 + l) * 4);
    float4 wv = *(const float4*)(wr + (p * 64 + l) * 4);
    s += xv.x * wv.x + xv.y * wv.y + xv.z * wv.z + xv.w * wv.w;
  }
#pragma unroll
  for (int off = 32; off; off >>= 1) s += __shfl_xor(s, off);
  if (l == 0) { logits[t] = s; out_lg[t] = s; }
}

// ---------- top-k mask by rank counting (ties: lower index wins) ----------
// grid (32, 2): 64 tokens per block, 4 threads scan quarters per token
__global__ void k_mask(const float* __restrict__ logits, float* __restrict__ mask) {
  __shared__ float lg[2048];
  int b = blockIdx.y;
  const float* lp = logits + b * 2048;
  for (int j = threadIdx.x; j < 2048; j += 256) lg[j] = lp[j];
  __syncthreads();
  int t = threadIdx.x >> 2, qtr = threadIdx.x & 3;
  int i = blockIdx.x * 64 + t;
  float my = lg[i];
  int cnt = 0;
  for (int j = qtr * 512; j < qtr * 512 + 512; j += 4) {
    float4 v = *(const float4*)&lg[j];
    cnt += (v.x > my) || (v.x == my && (j + 0) < i);
    cnt += (v.y > my) || (v.y == my && (j + 1) < i);
    cnt += (v.z > my) || (v.z == my && (j + 2) < i);
    cnt += (v.w > my) || (v.w == my && (j + 3) < i);
  }
  cnt += __shfl_xor(cnt, 1);
  cnt += __shfl_xor(cnt, 2);
  if (qtr == 0) mask[b * 2048 + i] = (cnt < 1024) ? 1.0f : 0.0f;
}

// ---------- LayerNorm (fp32 in, bf16 out); one wave per token ----------
__global__ void k_ln(const float* __restrict__ x, const float* __restrict__ g,
                     const float* __restrict__ bb, u16* __restrict__ out) {
  int t = blockIdx.x * 4 + (threadIdx.x >> 6);
  int l = threadIdx.x & 63;
  const float* xp = x + (size_t)t * 1024;
  float4 xv[4];
  float s = 0.f, sq = 0.f;
#pragma unroll
  for (int p = 0; p < 4; ++p) {
    xv[p] = *(const float4*)(xp + (p * 64 + l) * 4);
    s += xv[p].x + xv[p].y + xv[p].z + xv[p].w;
    sq += xv[p].x * xv[p].x + xv[p].y * xv[p].y + xv[p].z * xv[p].z + xv[p].w * xv[p].w;
  }
#pragma unroll
  for (int off = 32; off; off >>= 1) { s += __shfl_xor(s, off); sq += __shfl_xor(sq, off); }
  float mu = s * (1.f / 1024.f);
  float var = sq * (1.f / 1024.f) - mu * mu;
  float rs = rsqrtf(var + 1e-6f);
#pragma unroll
  for (int p = 0; p < 4; ++p) {
    float4 gv = *(const float4*)(g + (p * 64 + l) * 4);
    float4 bv = *(const float4*)(bb + (p * 64 + l) * 4);
    ushort4v o;
    o.x = f2bfu((xv[p].x - mu) * rs * gv.x + bv.x);
    o.y = f2bfu((xv[p].y - mu) * rs * gv.y + bv.y);
    o.z = f2bfu((xv[p].z - mu) * rs * gv.z + bv.z);
    o.w = f2bfu((xv[p].w - mu) * rs * gv.w + bv.w);
    *(ushort4v*)(out + (size_t)t * 1024 + (p * 64 + l) * 4) = o;
  }
}

// ---------- V transpose: V[b,s,h*64+d] -> VT[bh][d][s] (both sides coalesced) ----------
// grid (16, 32), 256 threads; wave handles 32 s for all 64 d (lane = d)
__global__ void k_vtrans(const u16* __restrict__ V, u16* __restrict__ VT) {
  int bh = blockIdx.y;
  int b = bh >> 4, h = bh & 15;
  int w = threadIdx.x >> 6, l = threadIdx.x & 63;
  int s0 = (blockIdx.x * 4 + w) * 32;
  const u16* vb = V + ((size_t)b * 2048) * 1024 + h * 64 + l;
  u16 vals[32];
#pragma unroll
  for (int j = 0; j < 32; ++j) vals[j] = vb[(size_t)(s0 + j) * 1024];
  u16* ob = VT + ((size_t)bh * 64 + l) * 2048 + s0;
#pragma unroll
  for (int c = 0; c < 4; ++c) {
    short8 o;
#pragma unroll
    for (int j = 0; j < 8; ++j) o[j] = (short)vals[c * 8 + j];
    *(short8*)&ob[c * 8] = o;
  }
}

// ---------- common 128x128xBK64 GEMM core: C = A[M,K] * W[N,K]^T ----------
__device__ __forceinline__ void gemm_core64(
    const u16* __restrict__ A, const u16* __restrict__ W,
    u16 (&Al)[2][128][64], u16 (&Bl)[2][128][64],
    int m0, int n0, int K, f32x4 (&acc)[4][4]) {
  const int tid = threadIdx.x, w = tid >> 6, l = tid & 63;
  const int wr = (w >> 1) * 64, wc = (w & 1) * 64;
#pragma unroll
  for (int mt = 0; mt < 4; ++mt)
#pragma unroll
    for (int nt = 0; nt < 4; ++nt) acc[mt][nt] = (f32x4){0.f, 0.f, 0.f, 0.f};
  const int nsteps = K >> 6;

  auto stage = [&](int bf, int t) {
#pragma unroll
    for (int i = 0; i < 4; ++i) {
      const int bc = (i * 4 + w) * 64;
      const int chunk = bc + l;
      const int row = chunk >> 3, cc = chunk & 7;
      gld16(A + (size_t)(m0 + row) * K + t * 64 + cc * 8, (char*)(&Al[bf][0][0]) + bc * 16);
      gld16(W + (size_t)(n0 + row) * K + t * 64 + cc * 8, (char*)(&Bl[bf][0][0]) + bc * 16);
    }
  };

  stage(0, 0);
  for (int t = 0; t < nsteps; ++t) {
    __syncthreads();
    if (t + 1 < nsteps) stage((t + 1) & 1, t + 1);
    const int bf = t & 1;
#pragma unroll
    for (int kk = 0; kk < 2; ++kk) {
      const int ko = kk * 32 + (l >> 4) * 8;
      short8 af[4], bv[4];
#pragma unroll
      for (int mt = 0; mt < 4; ++mt) af[mt] = *(const short8*)&Al[bf][wr + mt * 16 + (l & 15)][ko];
#pragma unroll
      for (int nt = 0; nt < 4; ++nt) bv[nt] = *(const short8*)&Bl[bf][wc + nt * 16 + (l & 15)][ko];
#pragma unroll
      for (int mt = 0; mt < 4; ++mt)
#pragma unroll
        for (int nt = 0; nt < 4; ++nt)
          acc[mt][nt] = mfma16(af[mt], bv[nt], acc[mt][nt]);
    }
  }
}

// ---------- fused QKV projection (bf16 out) ----------
__global__ __launch_bounds__(256, 2)
void k_qkv(const u16* __restrict__ A,
           const u16* __restrict__ W0, const u16* __restrict__ W1, const u16* __restrict__ W2,
           u16* __restrict__ O0, u16* __restrict__ O1, u16* __restrict__ O2, int K) {
  __shared__ alignas(16) u16 Al[2][128][64];
  __shared__ alignas(16) u16 Bl[2][128][64];
  const int sel = blockIdx.x >> 3;
  const u16* W = sel == 0 ? W0 : (sel == 1 ? W1 : W2);
  u16* Ot = sel == 0 ? O0 : (sel == 1 ? O1 : O2);
  const int n0 = (blockIdx.x & 7) * 128, m0 = blockIdx.y * 128;
  f32x4 acc[4][4];
  gemm_core64(A, W, Al, Bl, m0, n0, K, acc);
  const int tid = threadIdx.x, w = tid >> 6, l = tid & 63;
  const int wr = (w >> 1) * 64, wc = (w & 1) * 64;
#pragma unroll
  for (int mt = 0; mt < 4; ++mt)
#pragma unroll
    for (int nt = 0; nt < 4; ++nt) {
      int row = m0 + wr + mt * 16 + ((l >> 4) << 2);
      int col = n0 + wc + nt * 16 + (l & 15);
#pragma unroll
      for (int r = 0; r < 4; ++r)
        Ot[(size_t)(row + r) * 1024 + col] = f2bfu(acc[mt][nt][r]);
    }
}

// ---------- projection GEMM with fused residual + routing-mask epilogue ----------
__global__ __launch_bounds__(256, 2)
void k_proj_resid(const u16* __restrict__ A, const u16* __restrict__ W,
                  const float* __restrict__ resid, const float* __restrict__ mask,
                  float* __restrict__ out, int N, int K) {
  __shared__ alignas(16) u16 Al[2][128][64];
  __shared__ alignas(16) u16 Bl[2][128][64];
  const int n0 = blockIdx.x * 128, m0 = blockIdx.y * 128;
  f32x4 acc[4][4];
  gemm_core64(A, W, Al, Bl, m0, n0, K, acc);
  const int tid = threadIdx.x, w = tid >> 6, l = tid & 63;
  const int wr = (w >> 1) * 64, wc = (w & 1) * 64;
#pragma unroll
  for (int mt = 0; mt < 4; ++mt)
#pragma unroll
    for (int nt = 0; nt < 4; ++nt) {
      int row = m0 + wr + mt * 16 + ((l >> 4) << 2);
      int col = n0 + wc + nt * 16 + (l & 15);
#pragma unroll
      for (int r = 0; r < 4; ++r) {
        size_t idx = (size_t)(row + r) * N + col;
        out[idx] = resid[idx] + mask[row + r] * acc[mt][nt][r];
      }
    }
}

// ---------- fused dual gate/up GEMM (BK=32) with silu(g)*u epilogue ----------
__global__ __launch_bounds__(256, 2)
void k_ffn_dual(const u16* __restrict__ A, const u16* __restrict__ Wg, const u16* __restrict__ Wu,
                u16* __restrict__ H, int N, int K) {
  __shared__ alignas(16) u16 Al[2][128][32];
  __shared__ alignas(16) u16 Bgl[2][128][32];
  __shared__ alignas(16) u16 Bul[2][128][32];
  const int tid = threadIdx.x, w = tid >> 6, l = tid & 63;
  const int n0 = blockIdx.x * 128, m0 = blockIdx.y * 128;
  const int wr = (w >> 1) * 64, wc = (w & 1) * 64;
  f32x4 ag[4][4], au[4][4];
#pragma unroll
  for (int mt = 0; mt < 4; ++mt)
#pragma unroll
    for (int nt = 0; nt < 4; ++nt) {
      ag[mt][nt] = (f32x4){0.f, 0.f, 0.f, 0.f};
      au[mt][nt] = (f32x4){0.f, 0.f, 0.f, 0.f};
    }
  const int nsteps = K >> 5;

  auto stage = [&](int bf, int t) {
#pragma unroll
    for (int i = 0; i < 2; ++i) {
      const int bc = (i * 4 + w) * 64;
      const int chunk = bc + l;
      const int row = chunk >> 2, cc = chunk & 3;
      const size_t ao = (size_t)(m0 + row) * K + t * 32 + cc * 8;
      const size_t bo = (size_t)(n0 + row) * K + t * 32 + cc * 8;
      gld16(A + ao,  (char*)(&Al[bf][0][0])  + bc * 16);
      gld16(Wg + bo, (char*)(&Bgl[bf][0][0]) + bc * 16);
      gld16(Wu + bo, (char*)(&Bul[bf][0][0]) + bc * 16);
    }
  };

  stage(0, 0);
  for (int t = 0; t < nsteps; ++t) {
    __syncthreads();
    if (t + 1 < nsteps) stage((t + 1) & 1, t + 1);
    const int bf = t & 1;
    const int ko = (l >> 4) * 8;
    short8 af[4], bg[4], bu[4];
#pragma unroll
    for (int mt = 0; mt < 4; ++mt) af[mt] = *(const short8*)&Al[bf][wr + mt * 16 + (l & 15)][ko];
#pragma unroll
    for (int nt = 0; nt < 4; ++nt) {
      bg[nt] = *(const short8*)&Bgl[bf][wc + nt * 16 + (l & 15)][ko];
      bu[nt] = *(const short8*)&Bul[bf][wc + nt * 16 + (l & 15)][ko];
    }
#pragma unroll
    for (int mt = 0; mt < 4; ++mt)
#pragma unroll
      for (int nt = 0; nt < 4; ++nt) {
        ag[mt][nt] = mfma16(af[mt], bg[nt], ag[mt][nt]);
        au[mt][nt] = mfma16(af[mt], bu[nt], au[mt][nt]);
      }
  }
#pragma unroll
  for (int mt = 0; mt < 4; ++mt)
#pragma unroll
    for (int nt = 0; nt < 4; ++nt) {
      int row = m0 + wr + mt * 16 + ((l >> 4) << 2);
      int col = n0 + wc + nt * 16 + (l & 15);
#pragma unroll
      for (int r = 0; r < 4; ++r) {
        float g = ag[mt][nt][r], u = au[mt][nt][r];
        float sg = g / (1.f + __expf(-g));
        H[(size_t)(row + r) * N + col] = f2bfu(sg * u);
      }
    }
}

// ---------- flash causal attention v3 ----------
// paired q-tiles (px, 31-px): every block does exactly 33 KV iterations.
// V pre-transposed globally (VT[bh][d][s]) -> conflict-free vector staging.
// K/VT tile loads for kt+1 prefetched into regs during kt compute (T14).
__global__ __launch_bounds__(256, 2)
void k_attn(const u16* __restrict__ Q, const u16* __restrict__ K,
            const u16* __restrict__ VT, u16* __restrict__ O) {
  const int S = 2048, HH = 1024;
  const int px = blockIdx.x, bh = blockIdx.y;
  const int b = bh >> 4, h = bh & 15;
  const int tid = threadIdx.x, w = tid >> 6, l = tid & 63;
  __shared__ alignas(16) u16 Kl[64][72];
  __shared__ alignas(16) u16 Vtl[64][72];
  __shared__ alignas(16) u16 Pl[4][16][72];
  const size_t base = ((size_t)b * S) * HH + h * 64;
  const u16* vtb = VT + ((size_t)bh * 64) * S;

  // staging slots: 2 chunks of 16B per thread per array
  const int r0 = tid >> 3,          cc0 = (tid & 7) * 8;
  const int r1 = (256 + tid) >> 3,  cc1 = (tid & 7) * 8;

  auto flash = [&](int qt) {
    const int qr0 = qt * 64 + w * 16 + ((l >> 4) << 2);
    const int qrow = qt * 64 + w * 16 + (l & 15);
    short8 qf[2];
#pragma unroll
    for (int kk = 0; kk < 2; ++kk)
      qf[kk] = *(const short8*)&Q[base + (size_t)qrow * HH + kk * 32 + (l >> 4) * 8];

    f32x4 accO[4];
    float m[4], ls[4];
#pragma unroll
    for (int dt = 0; dt < 4; ++dt) accO[dt] = (f32x4){0.f, 0.f, 0.f, 0.f};
#pragma unroll
    for (int r = 0; r < 4; ++r) { m[r] = -1e30f; ls[r] = 0.f; }

    short8 kreg0, kreg1, vreg0, vreg1;
    auto loadregs = [&](int kt) {
      kreg0 = *(const short8*)&K[base + (size_t)(kt * 64 + r0) * HH + cc0];
      kreg1 = *(const short8*)&K[base + (size_t)(kt * 64 + r1) * HH + cc1];
      vreg0 = *(const short8*)&vtb[(size_t)r0 * S + kt * 64 + cc0];
      vreg1 = *(const short8*)&vtb[(size_t)r1 * S + kt * 64 + cc1];
    };
    loadregs(0);

    for (int kt = 0; kt <= qt; ++kt) {
      __syncthreads();
      *(short8*)&Kl[r0][cc0]  = kreg0;
      *(short8*)&Kl[r1][cc1]  = kreg1;
      *(short8*)&Vtl[r0][cc0] = vreg0;
      *(short8*)&Vtl[r1][cc1] = vreg1;
      if (kt < qt) loadregs(kt + 1);
      __syncthreads();

      // QK^T : 4 column tiles of 16
      float p[4][4];
      const bool diag = (kt == qt);
      const int kcb = kt * 64 + (l & 15);
#pragma unroll
      for (int ct = 0; ct < 4; ++ct) {
        f32x4 a = (f32x4){0.f, 0.f, 0.f, 0.f};
#pragma unroll
        for (int kk = 0; kk < 2; ++kk) {
          short8 kf = *(const short8*)&Kl[ct * 16 + (l & 15)][kk * 32 + (l >> 4) * 8];
          a = mfma16(qf[kk], kf, a);
        }
#pragma unroll
        for (int r = 0; r < 4; ++r) {
          float v = a[r] * 0.125f;
          if (diag && (kcb + ct * 16) > (qr0 + r)) v = -1e30f;
          p[ct][r] = v;
        }
      }
      // online softmax; alpha is PER ROW r
#pragma unroll
      for (int r = 0; r < 4; ++r) {
        float mx = fmaxf(fmaxf(p[0][r], p[1][r]), fmaxf(p[2][r], p[3][r]));
#pragma unroll
        for (int off = 1; off < 16; off <<= 1) mx = fmaxf(mx, __shfl_xor(mx, off));
        float mn = fmaxf(m[r], mx);
        float alpha = __expf(m[r] - mn);
        m[r] = mn;
        float ps = 0.f;
#pragma unroll
        for (int ct = 0; ct < 4; ++ct) { float e = __expf(p[ct][r] - mn); p[ct][r] = e; ps += e; }
#pragma unroll
        for (int off = 1; off < 16; off <<= 1) ps += __shfl_xor(ps, off);
        ls[r] = ls[r] * alpha + ps;
#pragma unroll
        for (int dt = 0; dt < 4; ++dt) accO[dt][r] *= alpha;
      }
      // P (C-layout) -> wave-private LDS -> A-frag layout
#pragma unroll
      for (int ct = 0; ct < 4; ++ct)
#pragma unroll
        for (int r = 0; r < 4; ++r)
          Pl[w][((l >> 4) << 2) + r][ct * 16 + (l & 15)] = f2bfu(p[ct][r]);
      short8 pa[2];
#pragma unroll
      for (int kk = 0; kk < 2; ++kk)
        pa[kk] = *(const short8*)&Pl[w][l & 15][kk * 32 + (l >> 4) * 8];
      // PV
#pragma unroll
      for (int dt = 0; dt < 4; ++dt)
#pragma unroll
        for (int kk = 0; kk < 2; ++kk) {
          short8 vf = *(const short8*)&Vtl[dt * 16 + (l & 15)][kk * 32 + (l >> 4) * 8];
          accO[dt] = mfma16(pa[kk], vf, accO[dt]);
        }
    }
    // epilogue
#pragma unroll
    for (int dt = 0; dt < 4; ++dt)
#pragma unroll
      for (int r = 0; r < 4; ++r) {
        float v = accO[dt][r] / ls[r];
        O[base + (size_t)(qr0 + r) * HH + dt * 16 + (l & 15)] = f2bfu(v);
      }
  };

  flash(px);
  flash(31 - px);
}

extern "C" void kernel_launch(void* const* d_in, const int* in_sizes, int n_in,
                              void* d_out, int out_size, void* d_ws, size_t ws_size,
                              hipStream_t stream) {
  const float* x  = (const float*)d_in[0];
  const float* wr = (const float*)d_in[1];
  const float* g1 = (const float*)d_in[2];
  const float* b1 = (const float*)d_in[3];
  const float* wq = (const float*)d_in[4];
  const float* wk = (const float*)d_in[5];
  const float* wv = (const float*)d_in[6];
  const float* wo = (const float*)d_in[7];
  const float* g2 = (const float*)d_in[8];
  const float* b2 = (const float*)d_in[9];
  const float* wg = (const float*)d_in[10];
  const float* wu = (const float*)d_in[11];
  const float* wd = (const float*)d_in[12];

  float* out_x  = (float*)d_out;
  float* out_lg = out_x + (size_t)4096 * 1024;

  char* p = (char*)d_ws;
  float* mask   = (float*)p;             p += 16384;
  float* logits = (float*)p;             p += 16384;
  u16* wq_b = (u16*)p;                   p += (size_t)1048576 * 2;
  u16* wk_b = (u16*)p;                   p += (size_t)1048576 * 2;
  u16* wv_b = (u16*)p;                   p += (size_t)1048576 * 2;
  u16* wo_b = (u16*)p;                   p += (size_t)1048576 * 2;
  u16* wg_b = (u16*)p;                   p += (size_t)4194304 * 2;
  u16* wu_b = (u16*)p;                   p += (size_t)4194304 * 2;
  u16* wd_b = (u16*)p;                   p += (size_t)4194304 * 2;
  u16* xn   = (u16*)p;                   p += (size_t)4194304 * 2;  // reused for xn2
  u16* q_b  = (u16*)p;                   p += (size_t)4194304 * 2;
  u16* k_b  = (u16*)p;                   p += (size_t)4194304 * 2;
  u16* v_b  = (u16*)p;                   p += (size_t)4194304 * 2;
  u16* ao_b = (u16*)p;                   p += (size_t)4194304 * 2;
  u16* vt_b = (u16*)p;                   p += (size_t)4194304 * 2;  // VT[bh][64][2048]
  u16* h_b  = q_b;  // [4096][4096] bf16 reuses q/k/v/ao region after attention+O-proj

  // weight conversions (single launch)
  k_cvt7<<<dim3(4096, 7), 256, 0, stream>>>(wq, wk, wv, wo, wg, wu, wd,
                                            wq_b, wk_b, wv_b, wo_b, wg_b, wu_b, wd_b);

  // router + mask
  k_router<<<1024, 256, 0, stream>>>(x, wr, logits, out_lg);
  k_mask<<<dim3(32, 2), 256, 0, stream>>>(logits, mask);

  // attention sub-block
  k_ln<<<1024, 256, 0, stream>>>(x, g1, b1, xn);
  k_qkv<<<dim3(24, 32), 256, 0, stream>>>(xn, wq_b, wk_b, wv_b, q_b, k_b, v_b, 1024);
  k_vtrans<<<dim3(16, 32), 256, 0, stream>>>(v_b, vt_b);
  k_attn<<<dim3(16, 32), 256, 0, stream>>>(q_b, k_b, vt_b, ao_b);
  k_proj_resid<<<dim3(8, 32), 256, 0, stream>>>(ao_b, wo_b, x, mask, out_x, 1024, 1024);

  // FFN sub-block
  k_ln<<<1024, 256, 0, stream>>>(out_x, g2, b2, xn);
  k_ffn_dual<<<dim3(32, 32), 256, 0, stream>>>(xn, wg_b, wu_b, h_b, 4096, 1024);
  k_proj_resid<<<dim3(8, 32), 256, 0, stream>>>(h_b, wd_b, out_x, mask, out_x, 1024, 4096);
}